// Round 5
// baseline (224.062 us; speedup 1.0000x reference)
//
#include <hip/hip_runtime.h>

// ---------------------------------------------------------------------------
// Masked SDPA, B=2 H=16 S=2048 D=64, fp32 in/out.
// Prepass 1: K -> bf16 swizzled tile images, V -> bf16 transposed swizzled
//            tile images (4KB per (bh,ktile)) in d_ws (16MB).
// Prepass 2 (only if ws_size >= 17MB): mask -> bit-packed words.
// Main: flash-style online softmax, 64 q-rows/block (4 waves x 16 rows),
//       KB=32 k-tile, mfma_f32_16x16x32_bf16 for QK^T (swapped) and PV.
//       Template<USE_BITS>: mask from bit words (fast) or direct mask reads
//       (fallback when workspace can't hold the bits buffer).
// ---------------------------------------------------------------------------

typedef __attribute__((ext_vector_type(8))) short  short8;   // 8 bf16 (A/B frag)
typedef __attribute__((ext_vector_type(4))) float  floatx4;  // C/D frag

constexpr int   B_  = 2, H_ = 16, S_ = 2048, D_ = 64;
constexpr int   BH_ = B_ * H_;
constexpr int   KB_ = 32;          // k-tile width
constexpr int   NT_ = S_ / KB_;    // 64 k-tiles
constexpr float SCALE_   = 0.125f; // 1/sqrt(64)
constexpr float MASKVAL_ = -1e30f;
constexpr float MCLAMP_  = -1e29f;

__device__ __forceinline__ unsigned short f2bf(float f) {
  union { float f; unsigned u; } v; v.f = f;
  unsigned r = v.u + 0x7fffu + ((v.u >> 16) & 1u);  // RNE
  return (unsigned short)(r >> 16);
}
__device__ __forceinline__ unsigned pk2(float lo, float hi) {
  return (unsigned)f2bf(lo) | ((unsigned)f2bf(hi) << 16);
}

// ---------------------------------------------------------------------------
// Prepass 1: K/V bf16 images.
// Kimg: byte = krow*128 + ((dslot ^ (krow&7))<<4), dslot = d/8.
// Vimg: byte = d*64 + ((kslot ^ (d&3))<<4),  kslot = k/8 (V^T: d-major).
// ---------------------------------------------------------------------------
__global__ __launch_bounds__(256) void prep_kernel(
    const float* __restrict__ k, const float* __restrict__ v,
    uint4* __restrict__ kimg, uint4* __restrict__ vimg) {
  int blk = blockIdx.x;
  int tid = threadIdx.x;
  int half = BH_ * NT_;
  if (blk < half) {
    int bh = blk / NT_, kt = blk % NT_;
    int krow = tid >> 3, d08 = tid & 7;
    const float* src = k + ((size_t)bh * S_ + (size_t)kt * KB_ + krow) * D_ + d08 * 8;
    float4 f0 = *(const float4*)src;
    float4 f1 = *(const float4*)(src + 4);
    uint4 w;
    w.x = pk2(f0.x, f0.y); w.y = pk2(f0.z, f0.w);
    w.z = pk2(f1.x, f1.y); w.w = pk2(f1.z, f1.w);
    int slot = d08 ^ (krow & 7);
    kimg[(size_t)blk * 256 + krow * 8 + slot] = w;
  } else {
    int blk2 = blk - half;
    int bh = blk2 / NT_, kt = blk2 % NT_;
    int d = tid & 63, k08 = tid >> 6;
    const float* src = v + ((size_t)bh * S_ + (size_t)kt * KB_ + k08 * 8) * D_ + d;
    float e[8];
#pragma unroll
    for (int j = 0; j < 8; ++j) e[j] = src[(size_t)j * D_];
    uint4 w;
    w.x = pk2(e[0], e[1]); w.y = pk2(e[2], e[3]);
    w.z = pk2(e[4], e[5]); w.w = pk2(e[6], e[7]);
    int slot = k08 ^ (d & 3);
    vimg[(size_t)blk2 * 256 + d * 4 + slot] = w;
  }
}

// ---------------------------------------------------------------------------
// Prepass 2: mask -> bit words. __ballot packs 64 predicates; lane 0 stores
// two consecutive words. Dtype autodetect: any of first 16 u32 > 1 => bytes.
// ---------------------------------------------------------------------------
__global__ __launch_bounds__(256) void maskpack_kernel(
    const void* __restrict__ mask, unsigned* __restrict__ bits) {
  const unsigned* mw = (const unsigned*)mask;
  bool is_bytes = false;
#pragma unroll
  for (int i = 0; i < 16; ++i) is_bytes |= (mw[i] > 1u);

  size_t gid = (size_t)blockIdx.x * 256 + threadIdx.x;
  unsigned v = is_bytes ? (unsigned)((const unsigned char*)mask)[gid]
                        : ((const unsigned*)mask)[gid];
  unsigned long long bal = __ballot(v != 0u);
  if ((threadIdx.x & 63) == 0) {
    size_t w = gid >> 5;   // first of two word slots for this wave
    *(uint2*)&bits[w] = make_uint2((unsigned)bal, (unsigned)(bal >> 32));
  }
}

// ---------------------------------------------------------------------------
// Main attention kernel. Grid: BH*32 blocks (bh = bid>>5, qtile = bid&31).
// 256 threads = 4 waves, each wave owns 16 q-rows.
// Swapped QK^T: C[krow][qcol] = mfma(A=K_tile, B=Q^T); lane (lq=lane&15,
// g=lane>>4) element i holds s[k=16*sub+4g+i][q=lq].
// USE_BITS: mask from packed bit words; else direct mask reads (autodetect
// int32 vs byte layout, wave-uniform branch).
// ---------------------------------------------------------------------------
template <bool USE_BITS>
__global__ __launch_bounds__(256) void attn_kernel(
    const float* __restrict__ q, const unsigned* __restrict__ mbits,
    const void* __restrict__ mask_raw,
    const uint4* __restrict__ kimg, const uint4* __restrict__ vimg,
    float* __restrict__ out) {
  __shared__ uint4 KtL[256];                    // 4KB : K tile image
  __shared__ uint4 VtL[256];                    // 4KB : V^T tile image
  __shared__ __align__(16) short Pb[4 * 640];   // 5KB : per-wave P (16x32 bf16, 80B stride)

  const int tid  = threadIdx.x;
  const int wid  = tid >> 6;
  const int lane = tid & 63;
  const int lq   = lane & 15;
  const int g    = lane >> 4;
  const int bid  = blockIdx.x;
  const int bh   = bid >> 5;
  const int qt   = bid & 31;
  const int b    = bh >> 4;        // H=16

  const int qrow = qt * 64 + wid * 16 + lq;
  const float* qp = q + ((size_t)bh * S_ + qrow) * D_;

  // direct-mask fallback: detect layout once (uniform)
  bool is_bytes = false;
  if (!USE_BITS) {
    const unsigned* mw0 = (const unsigned*)mask_raw;
#pragma unroll
    for (int i = 0; i < 16; ++i) is_bytes |= (mw0[i] > 1u);
  }

  // Q fragments (B-operand): lane holds Q[lq][8g + 32t + j]
  short8 qf[2];
#pragma unroll
  for (int t = 0; t < 2; ++t) {
    float4 f0 = *(const float4*)(qp + 8 * g + 32 * t);
    float4 f1 = *(const float4*)(qp + 8 * g + 32 * t + 4);
    short8 s;
    s[0] = (short)f2bf(f0.x); s[1] = (short)f2bf(f0.y);
    s[2] = (short)f2bf(f0.z); s[3] = (short)f2bf(f0.w);
    s[4] = (short)f2bf(f1.x); s[5] = (short)f2bf(f1.y);
    s[6] = (short)f2bf(f1.z); s[7] = (short)f2bf(f1.w);
    qf[t] = s;
  }

  const unsigned* mrow = mbits + ((size_t)b * S_ + qrow) * (size_t)NT_;
  const size_t mask_row_off = ((size_t)b * S_ + qrow) * (size_t)S_;

  float m_run = -1e30f, l_run = 0.0f;
  floatx4 acc[4];
#pragma unroll
  for (int c = 0; c < 4; ++c) acc[c] = (floatx4){0.f, 0.f, 0.f, 0.f};

  const size_t imgbase = (size_t)bh * NT_ * 256;

  // prologue: stage tile 0
  KtL[tid] = kimg[imgbase + tid];
  VtL[tid] = vimg[imgbase + tid];
  __syncthreads();

  char* ldsK = (char*)KtL;
  char* ldsV = (char*)VtL;
  char* ldsP = (char*)Pb + wid * 1280 + lq * 80;

  for (int t = 0; t < NT_; ++t) {
    // prefetch next tile into regs
    uint4 kn, vn;
    if (t + 1 < NT_) {
      kn = kimg[imgbase + (size_t)(t + 1) * 256 + tid];
      vn = vimg[imgbase + (size_t)(t + 1) * 256 + tid];
    }
    const int kb = t * KB_;

    // mask nibbles: mlo bits i -> k=kb+4g+i, mhi bits i -> k=kb+16+4g+i
    unsigned mlo, mhi;
    if (USE_BITS) {
      unsigned mw = mrow[t];
      mlo = mw >> (4 * g);
      mhi = mw >> (16 + 4 * g);
    } else if (!is_bytes) {
      const unsigned* m32 = (const unsigned*)mask_raw + mask_row_off;
      uint4 a = *(const uint4*)(m32 + kb + 4 * g);
      uint4 c = *(const uint4*)(m32 + kb + 16 + 4 * g);
      mlo = (a.x ? 1u : 0u) | (a.y ? 2u : 0u) | (a.z ? 4u : 0u) | (a.w ? 8u : 0u);
      mhi = (c.x ? 1u : 0u) | (c.y ? 2u : 0u) | (c.z ? 4u : 0u) | (c.w ? 8u : 0u);
    } else {
      const unsigned char* m8 = (const unsigned char*)mask_raw + mask_row_off;
      uchar4 a = *(const uchar4*)(m8 + kb + 4 * g);
      uchar4 c = *(const uchar4*)(m8 + kb + 16 + 4 * g);
      mlo = (a.x ? 1u : 0u) | (a.y ? 2u : 0u) | (a.z ? 4u : 0u) | (a.w ? 8u : 0u);
      mhi = (c.x ? 1u : 0u) | (c.y ? 2u : 0u) | (c.z ? 4u : 0u) | (c.w ? 8u : 0u);
    }

    // QK^T: two k-sub-tiles, accumulate over d halves
    floatx4 c0 = (floatx4){0.f, 0.f, 0.f, 0.f};
    floatx4 c1 = (floatx4){0.f, 0.f, 0.f, 0.f};
#pragma unroll
    for (int tt = 0; tt < 2; ++tt) {
      const int sw = ((g + 4 * tt) ^ (lq & 7)) << 4;
      short8 a0 = *(const short8*)(ldsK + (size_t)lq * 128 + sw);
      short8 a1 = *(const short8*)(ldsK + (size_t)(16 + lq) * 128 + sw);
      c0 = __builtin_amdgcn_mfma_f32_16x16x32_bf16(a0, qf[tt], c0, 0, 0, 0);
      c1 = __builtin_amdgcn_mfma_f32_16x16x32_bf16(a1, qf[tt], c1, 0, 0, 0);
    }

    // scale + mask (mask bit set -> -inf)
    float s0 = (mlo & 1u) ? MASKVAL_ : c0[0] * SCALE_;
    float s1 = (mlo & 2u) ? MASKVAL_ : c0[1] * SCALE_;
    float s2 = (mlo & 4u) ? MASKVAL_ : c0[2] * SCALE_;
    float s3 = (mlo & 8u) ? MASKVAL_ : c0[3] * SCALE_;
    float s4 = (mhi & 1u) ? MASKVAL_ : c1[0] * SCALE_;
    float s5 = (mhi & 2u) ? MASKVAL_ : c1[1] * SCALE_;
    float s6 = (mhi & 4u) ? MASKVAL_ : c1[2] * SCALE_;
    float s7 = (mhi & 8u) ? MASKVAL_ : c1[3] * SCALE_;

    // online softmax stats for q-column lq (values spread over 4 g-lanes)
    float tm = fmaxf(fmaxf(fmaxf(s0, s1), fmaxf(s2, s3)),
                     fmaxf(fmaxf(s4, s5), fmaxf(s6, s7)));
    tm = fmaxf(tm, __shfl_xor(tm, 16));
    tm = fmaxf(tm, __shfl_xor(tm, 32));
    float m_new = fmaxf(m_run, tm);
    float mu = fmaxf(m_new, MCLAMP_);
    float corr = __expf(fmaxf(m_run, MCLAMP_) - mu);
    float p0 = __expf(s0 - mu), p1 = __expf(s1 - mu);
    float p2 = __expf(s2 - mu), p3 = __expf(s3 - mu);
    float p4 = __expf(s4 - mu), p5 = __expf(s5 - mu);
    float p6 = __expf(s6 - mu), p7 = __expf(s7 - mu);
    float ts = ((p0 + p1) + (p2 + p3)) + ((p4 + p5) + (p6 + p7));
    ts += __shfl_xor(ts, 16);
    ts += __shfl_xor(ts, 32);
    l_run = l_run * corr + ts;
    m_run = m_new;

    // P -> per-wave LDS (row lq, k = 16*sub + 4g + i), bf16-packed
    *(uint2*)(ldsP + 8 * g)      = make_uint2(pk2(p0, p1), pk2(p2, p3));
    *(uint2*)(ldsP + 32 + 8 * g) = make_uint2(pk2(p4, p5), pk2(p6, p7));
    asm volatile("s_waitcnt lgkmcnt(0)" ::: "memory");
    __builtin_amdgcn_sched_barrier(0);
    short8 pa = *(const short8*)(ldsP + 16 * g);   // P[lq][8g..8g+7]

    // rescale O accumulator: O row = 4g+i, corr for that q-row lives at lane 4g+i
    float cr0 = __shfl(corr, 4 * g + 0);
    float cr1 = __shfl(corr, 4 * g + 1);
    float cr2 = __shfl(corr, 4 * g + 2);
    float cr3 = __shfl(corr, 4 * g + 3);
#pragma unroll
    for (int c = 0; c < 4; ++c) {
      floatx4 a = acc[c];
      a[0] *= cr0; a[1] *= cr1; a[2] *= cr2; a[3] *= cr3;
      acc[c] = a;
    }

    // PV: B-frag from swizzled V^T tile: lane holds V[kb+8g+j][16c+lq]
#pragma unroll
    for (int c = 0; c < 4; ++c) {
      short8 vb = *(const short8*)(ldsV + (size_t)(16 * c + lq) * 64 +
                                   (((g ^ (lq & 3))) << 4));
      acc[c] = __builtin_amdgcn_mfma_f32_16x16x32_bf16(pa, vb, acc[c], 0, 0, 0);
    }

    __syncthreads();                 // everyone done reading tile t
    if (t + 1 < NT_) { KtL[tid] = kn; VtL[tid] = vn; }
    __syncthreads();                 // tile t+1 staged
  }

  // epilogue: divide by l (route to O layout), store fp32
  float li0 = __shfl(l_run, 4 * g + 0);
  float li1 = __shfl(l_run, 4 * g + 1);
  float li2 = __shfl(l_run, 4 * g + 2);
  float li3 = __shfl(l_run, 4 * g + 3);
  float r0 = 1.0f / li0, r1 = 1.0f / li1, r2 = 1.0f / li2, r3 = 1.0f / li3;
  float* op = out + ((size_t)bh * S_ + (size_t)qt * 64 + wid * 16) * D_;
#pragma unroll
  for (int c = 0; c < 4; ++c) {
    op[(size_t)(4 * g + 0) * D_ + 16 * c + lq] = acc[c][0] * r0;
    op[(size_t)(4 * g + 1) * D_ + 16 * c + lq] = acc[c][1] * r1;
    op[(size_t)(4 * g + 2) * D_ + 16 * c + lq] = acc[c][2] * r2;
    op[(size_t)(4 * g + 3) * D_ + 16 * c + lq] = acc[c][3] * r3;
  }
}

extern "C" void kernel_launch(void* const* d_in, const int* in_sizes, int n_in,
                              void* d_out, int out_size, void* d_ws, size_t ws_size,
                              hipStream_t stream) {
  const float* q = (const float*)d_in[0];
  const float* k = (const float*)d_in[1];
  const float* v = (const float*)d_in[2];
  const void*  mask = d_in[3];

  constexpr size_t IMG_BYTES  = (size_t)BH_ * S_ * D_ * 2;       // 8MB each
  constexpr size_t BITS_BYTES = (size_t)B_ * S_ * (S_ / 8);      // 1MB

  uint4*    kimg = (uint4*)d_ws;
  uint4*    vimg = (uint4*)((char*)d_ws + IMG_BYTES);
  unsigned* bits = (unsigned*)((char*)d_ws + 2 * IMG_BYTES);

  prep_kernel<<<2 * BH_ * NT_, 256, 0, stream>>>(k, v, kimg, vimg);

  if (ws_size >= 2 * IMG_BYTES + BITS_BYTES) {
    maskpack_kernel<<<(B_ * S_ * S_) / 256, 256, 0, stream>>>(mask, bits);
    attn_kernel<true><<<BH_ * 32, 256, 0, stream>>>(q, bits, mask, kimg, vimg,
                                                    (float*)d_out);
  } else {
    attn_kernel<false><<<BH_ * 32, 256, 0, stream>>>(q, bits, mask, kimg, vimg,
                                                     (float*)d_out);
  }
}

// Round 8
// 209.613 us; speedup vs baseline: 1.0689x; 1.0689x over previous
//
#include <hip/hip_runtime.h>

// ---------------------------------------------------------------------------
// Masked SDPA, B=2 H=16 S=2048 D=64, fp32 in/out.
// prep_kernel (merged): K -> bf16 swizzled tile images, V -> bf16 transposed
//   swizzled tile images, mask -> bit-packed words (ballot), all in d_ws.
// attn_kernel: flash online softmax, 64 q-rows/block (4 waves x 16 rows),
//   KB=32, mfma_f32_16x16x32_bf16 (swapped QK^T), double-buffered LDS with
//   ONE barrier/tile, defer-max (THR=8), cvt_pk bf16 packing, Q pre-scaled.
// ---------------------------------------------------------------------------

typedef __attribute__((ext_vector_type(8))) short  short8;   // 8 bf16 (A/B frag)
typedef __attribute__((ext_vector_type(4))) float  floatx4;  // C/D frag

constexpr int   B_  = 2, H_ = 16, S_ = 2048, D_ = 64;
constexpr int   BH_ = B_ * H_;
constexpr int   KB_ = 32;          // k-tile width
constexpr int   NT_ = S_ / KB_;    // 64 k-tiles
constexpr float SCALE_   = 0.125f; // 1/sqrt(64)
constexpr float MASKVAL_ = -1e30f;
constexpr float MCLAMP_  = -1e29f;
constexpr float DEFER_   = 8.0f;   // defer-max threshold (P <= e^8)

__device__ __forceinline__ unsigned short f2bf(float f) {
  union { float f; unsigned u; } v; v.f = f;
  unsigned r = v.u + 0x7fffu + ((v.u >> 16) & 1u);  // RNE
  return (unsigned short)(r >> 16);
}
__device__ __forceinline__ unsigned pk2(float lo, float hi) {
  return (unsigned)f2bf(lo) | ((unsigned)f2bf(hi) << 16);
}
__device__ __forceinline__ unsigned cvtpk(float lo, float hi) {
  unsigned r;
  asm("v_cvt_pk_bf16_f32 %0, %1, %2" : "=v"(r) : "v"(lo), "v"(hi));
  return r;
}

// ---------------------------------------------------------------------------
// Merged prepass. Blocks [0,half): K images. [half,2*half): V images.
// [2*half, ...): mask bit-pack (only launched when ws holds the bits buffer).
// Kimg: byte = krow*128 + ((dslot ^ (krow&7))<<4), dslot = d/8.
// Vimg: byte = d*64 + ((kslot ^ (d&3) ^ ((d>>2)&3))<<4), kslot = k/8.
//   (bit2 of d folded in: kills the lq/lq+4 2-way bank conflict on read)
// ---------------------------------------------------------------------------
__global__ __launch_bounds__(256) void prep_kernel(
    const float* __restrict__ k, const float* __restrict__ v,
    const void* __restrict__ mask,
    uint4* __restrict__ kimg, uint4* __restrict__ vimg,
    unsigned* __restrict__ bits) {
  int blk = blockIdx.x;
  int tid = threadIdx.x;
  constexpr int half = BH_ * NT_;
  if (blk < half) {
    int bh = blk / NT_, kt = blk % NT_;
    int krow = tid >> 3, d08 = tid & 7;
    const float* src = k + ((size_t)bh * S_ + (size_t)kt * KB_ + krow) * D_ + d08 * 8;
    float4 f0 = *(const float4*)src;
    float4 f1 = *(const float4*)(src + 4);
    uint4 w;
    w.x = pk2(f0.x, f0.y); w.y = pk2(f0.z, f0.w);
    w.z = pk2(f1.x, f1.y); w.w = pk2(f1.z, f1.w);
    int slot = d08 ^ (krow & 7);
    kimg[(size_t)blk * 256 + krow * 8 + slot] = w;
  } else if (blk < 2 * half) {
    int blk2 = blk - half;
    int bh = blk2 / NT_, kt = blk2 % NT_;
    int d = tid & 63, k08 = tid >> 6;
    const float* src = v + ((size_t)bh * S_ + (size_t)kt * KB_ + k08 * 8) * D_ + d;
    float e[8];
#pragma unroll
    for (int j = 0; j < 8; ++j) e[j] = src[(size_t)j * D_];
    uint4 w;
    w.x = pk2(e[0], e[1]); w.y = pk2(e[2], e[3]);
    w.z = pk2(e[4], e[5]); w.w = pk2(e[6], e[7]);
    int slot = k08 ^ (d & 3) ^ ((d >> 2) & 3);
    vimg[(size_t)blk2 * 256 + d * 4 + slot] = w;
  } else {
    // mask bit-pack; dtype autodetect (any of first 16 u32 > 1 => byte bools)
    const unsigned* mw = (const unsigned*)mask;
    bool is_bytes = false;
#pragma unroll
    for (int i = 0; i < 16; ++i) is_bytes |= (mw[i] > 1u);
    size_t gid = (size_t)(blk - 2 * half) * 256 + tid;
    unsigned vv = is_bytes ? (unsigned)((const unsigned char*)mask)[gid]
                           : ((const unsigned*)mask)[gid];
    unsigned long long bal = __ballot(vv != 0u);
    if ((tid & 63) == 0) {
      size_t w = gid >> 5;
      *(uint2*)&bits[w] = make_uint2((unsigned)bal, (unsigned)(bal >> 32));
    }
  }
}

// ---------------------------------------------------------------------------
// Main attention kernel. Grid: BH*32 blocks (bh = bid>>5, qtile = bid&31).
// 256 threads = 4 waves, each wave owns 16 q-rows.
// Swapped QK^T: C[krow][qcol] = mfma(A=K_tile, B=Q^T); lane (lq=lane&15,
// g=lane>>4) element i holds s[k=16*sub+4g+i][q=lq]. Q pre-scaled by SCALE.
// ---------------------------------------------------------------------------
template <bool USE_BITS>
__global__ __launch_bounds__(256) void attn_kernel(
    const float* __restrict__ q, const unsigned* __restrict__ mbits,
    const void* __restrict__ mask_raw,
    const uint4* __restrict__ kimg, const uint4* __restrict__ vimg,
    float* __restrict__ out) {
  __shared__ uint4 KtA[256], KtB[256];          // 2 x 4KB : K tile dbuf
  __shared__ uint4 VtA[256], VtB[256];          // 2 x 4KB : V^T tile dbuf
  __shared__ __align__(16) short Pb[4 * 640];   // 5KB : per-wave P (16x32 bf16, 80B stride)

  const int tid  = threadIdx.x;
  const int wid  = tid >> 6;
  const int lane = tid & 63;
  const int lq   = lane & 15;
  const int g    = lane >> 4;
  const int bid  = blockIdx.x;
  const int bh   = bid >> 5;
  const int qt   = bid & 31;
  const int b    = bh >> 4;        // H=16

  const int qrow = qt * 64 + wid * 16 + lq;
  const float* qp = q + ((size_t)bh * S_ + qrow) * D_;

  bool is_bytes = false;
  if (!USE_BITS) {
    const unsigned* mw0 = (const unsigned*)mask_raw;
#pragma unroll
    for (int i = 0; i < 16; ++i) is_bytes |= (mw0[i] > 1u);
  }

  // Q fragments (B-operand), pre-scaled by SCALE: lane holds Q[lq][8g+32t+j]
  short8 qf[2];
#pragma unroll
  for (int t = 0; t < 2; ++t) {
    float4 f0 = *(const float4*)(qp + 8 * g + 32 * t);
    float4 f1 = *(const float4*)(qp + 8 * g + 32 * t + 4);
    union { unsigned u[4]; short8 s; } cv;
    cv.u[0] = cvtpk(f0.x * SCALE_, f0.y * SCALE_);
    cv.u[1] = cvtpk(f0.z * SCALE_, f0.w * SCALE_);
    cv.u[2] = cvtpk(f1.x * SCALE_, f1.y * SCALE_);
    cv.u[3] = cvtpk(f1.z * SCALE_, f1.w * SCALE_);
    qf[t] = cv.s;
  }

  const unsigned* mrow = mbits + ((size_t)b * S_ + qrow) * (size_t)NT_;
  const size_t mask_row_off = ((size_t)b * S_ + qrow) * (size_t)S_;

  float m_run = -1e30f, l_run = 0.0f;
  floatx4 acc[4];
#pragma unroll
  for (int c = 0; c < 4; ++c) acc[c] = (floatx4){0.f, 0.f, 0.f, 0.f};

  const size_t imgbase = (size_t)bh * NT_ * 256;

  // prologue: stage tile 0 into buffer A
  KtA[tid] = kimg[imgbase + tid];
  VtA[tid] = vimg[imgbase + tid];
  __syncthreads();

  uint4* Kc = KtA; uint4* Vc = VtA;   // current tile
  uint4* Kn = KtB; uint4* Vn = VtB;   // next tile
  char* ldsP = (char*)Pb + wid * 1280 + lq * 80;

  for (int t = 0; t < NT_; ++t) {
    // prefetch next tile into regs (latency hidden under compute)
    uint4 kn, vn;
    if (t + 1 < NT_) {
      kn = kimg[imgbase + (size_t)(t + 1) * 256 + tid];
      vn = vimg[imgbase + (size_t)(t + 1) * 256 + tid];
    }
    const int kb = t * KB_;
    const char* ldsK = (const char*)Kc;
    const char* ldsV = (const char*)Vc;

    // mask nibbles: mlo bit i -> k=kb+4g+i, mhi bit i -> k=kb+16+4g+i
    unsigned mlo, mhi;
    if (USE_BITS) {
      unsigned mw = mrow[t];
      mlo = mw >> (4 * g);
      mhi = mw >> (16 + 4 * g);
    } else if (!is_bytes) {
      const unsigned* m32 = (const unsigned*)mask_raw + mask_row_off;
      uint4 a = *(const uint4*)(m32 + kb + 4 * g);
      uint4 c = *(const uint4*)(m32 + kb + 16 + 4 * g);
      mlo = (a.x ? 1u : 0u) | (a.y ? 2u : 0u) | (a.z ? 4u : 0u) | (a.w ? 8u : 0u);
      mhi = (c.x ? 1u : 0u) | (c.y ? 2u : 0u) | (c.z ? 4u : 0u) | (c.w ? 8u : 0u);
    } else {
      const unsigned char* m8 = (const unsigned char*)mask_raw + mask_row_off;
      uchar4 a = *(const uchar4*)(m8 + kb + 4 * g);
      uchar4 c = *(const uchar4*)(m8 + kb + 16 + 4 * g);
      mlo = (a.x ? 1u : 0u) | (a.y ? 2u : 0u) | (a.z ? 4u : 0u) | (a.w ? 8u : 0u);
      mhi = (c.x ? 1u : 0u) | (c.y ? 2u : 0u) | (c.z ? 4u : 0u) | (c.w ? 8u : 0u);
    }

    // QK^T: two k-sub-tiles, accumulate over d halves (scores pre-scaled via Q)
    floatx4 c0 = (floatx4){0.f, 0.f, 0.f, 0.f};
    floatx4 c1 = (floatx4){0.f, 0.f, 0.f, 0.f};
#pragma unroll
    for (int tt = 0; tt < 2; ++tt) {
      const int sw = ((g + 4 * tt) ^ (lq & 7)) << 4;
      short8 a0 = *(const short8*)(ldsK + (size_t)lq * 128 + sw);
      short8 a1 = *(const short8*)(ldsK + (size_t)(16 + lq) * 128 + sw);
      c0 = __builtin_amdgcn_mfma_f32_16x16x32_bf16(a0, qf[tt], c0, 0, 0, 0);
      c1 = __builtin_amdgcn_mfma_f32_16x16x32_bf16(a1, qf[tt], c1, 0, 0, 0);
    }

    // mask (bit set -> -1e30)
    float s0 = (mlo & 1u) ? MASKVAL_ : c0[0];
    float s1 = (mlo & 2u) ? MASKVAL_ : c0[1];
    float s2 = (mlo & 4u) ? MASKVAL_ : c0[2];
    float s3 = (mlo & 8u) ? MASKVAL_ : c0[3];
    float s4 = (mhi & 1u) ? MASKVAL_ : c1[0];
    float s5 = (mhi & 2u) ? MASKVAL_ : c1[1];
    float s6 = (mhi & 4u) ? MASKVAL_ : c1[2];
    float s7 = (mhi & 8u) ? MASKVAL_ : c1[3];

    // per-column tile max (column lq spread over 4 g-lanes)
    float tm = fmaxf(fmaxf(fmaxf(s0, s1), fmaxf(s2, s3)),
                     fmaxf(fmaxf(s4, s5), fmaxf(s6, s7)));
    tm = fmaxf(tm, __shfl_xor(tm, 16));
    tm = fmaxf(tm, __shfl_xor(tm, 32));

    // defer-max: only rescale when some column's max grew past mu+THR
    float mu = fmaxf(m_run, MCLAMP_);
    if (!__all(tm <= mu + DEFER_)) {
      float m_new = fmaxf(m_run, tm);
      float mu2 = fmaxf(m_new, MCLAMP_);
      float corr = __expf(mu - mu2);
      l_run *= corr;
      float cr0 = __shfl(corr, 4 * g + 0);
      float cr1 = __shfl(corr, 4 * g + 1);
      float cr2 = __shfl(corr, 4 * g + 2);
      float cr3 = __shfl(corr, 4 * g + 3);
#pragma unroll
      for (int c = 0; c < 4; ++c) {
        floatx4 a = acc[c];
        a[0] *= cr0; a[1] *= cr1; a[2] *= cr2; a[3] *= cr3;
        acc[c] = a;
      }
      m_run = m_new;
      mu = mu2;
    }

    float p0 = __expf(s0 - mu), p1 = __expf(s1 - mu);
    float p2 = __expf(s2 - mu), p3 = __expf(s3 - mu);
    float p4 = __expf(s4 - mu), p5 = __expf(s5 - mu);
    float p6 = __expf(s6 - mu), p7 = __expf(s7 - mu);
    float ts = ((p0 + p1) + (p2 + p3)) + ((p4 + p5) + (p6 + p7));
    ts += __shfl_xor(ts, 16);
    ts += __shfl_xor(ts, 32);
    l_run += ts;

    // P -> per-wave LDS (row lq, k = 16*sub + 4g + i), packed via v_cvt_pk
    *(uint2*)(ldsP + 8 * g)      = make_uint2(cvtpk(p0, p1), cvtpk(p2, p3));
    *(uint2*)(ldsP + 32 + 8 * g) = make_uint2(cvtpk(p4, p5), cvtpk(p6, p7));
    asm volatile("s_waitcnt lgkmcnt(0)" ::: "memory");
    __builtin_amdgcn_sched_barrier(0);
    short8 pa = *(const short8*)(ldsP + 16 * g);   // P[lq][8g..8g+7]

    // PV: B-frag from swizzled V^T tile: lane holds V[kb+8g+j][16c+lq]
#pragma unroll
    for (int c = 0; c < 4; ++c) {
      short8 vb = *(const short8*)(ldsV + (size_t)(16 * c + lq) * 64 +
                                   ((g ^ (lq & 3) ^ ((lq >> 2) & 3)) << 4));
      acc[c] = __builtin_amdgcn_mfma_f32_16x16x32_bf16(pa, vb, acc[c], 0, 0, 0);
    }

    // stage next tile into the other buffer; ONE barrier per iteration.
    if (t + 1 < NT_) { Kn[tid] = kn; Vn[tid] = vn; }
    __syncthreads();
    uint4* tk = Kc; Kc = Kn; Kn = tk;
    uint4* tv = Vc; Vc = Vn; Vn = tv;
  }

  // epilogue: divide by l (route to O layout), store fp32
  float li0 = __shfl(l_run, 4 * g + 0);
  float li1 = __shfl(l_run, 4 * g + 1);
  float li2 = __shfl(l_run, 4 * g + 2);
  float li3 = __shfl(l_run, 4 * g + 3);
  float r0 = 1.0f / li0, r1 = 1.0f / li1, r2 = 1.0f / li2, r3 = 1.0f / li3;
  float* op = out + ((size_t)bh * S_ + (size_t)qt * 64 + wid * 16) * D_;
#pragma unroll
  for (int c = 0; c < 4; ++c) {
    op[(size_t)(4 * g + 0) * D_ + 16 * c + lq] = acc[c][0] * r0;
    op[(size_t)(4 * g + 1) * D_ + 16 * c + lq] = acc[c][1] * r1;
    op[(size_t)(4 * g + 2) * D_ + 16 * c + lq] = acc[c][2] * r2;
    op[(size_t)(4 * g + 3) * D_ + 16 * c + lq] = acc[c][3] * r3;
  }
}

extern "C" void kernel_launch(void* const* d_in, const int* in_sizes, int n_in,
                              void* d_out, int out_size, void* d_ws, size_t ws_size,
                              hipStream_t stream) {
  const float* q = (const float*)d_in[0];
  const float* k = (const float*)d_in[1];
  const float* v = (const float*)d_in[2];
  const void*  mask = d_in[3];

  constexpr size_t IMG_BYTES  = (size_t)BH_ * S_ * D_ * 2;       // 8MB each
  constexpr size_t BITS_BYTES = (size_t)B_ * S_ * (S_ / 8);      // 1MB
  constexpr int    PREP_BLKS  = 2 * BH_ * NT_;
  constexpr int    MASK_BLKS  = (B_ * S_ * S_) / 256;

  uint4*    kimg = (uint4*)d_ws;
  uint4*    vimg = (uint4*)((char*)d_ws + IMG_BYTES);
  unsigned* bits = (unsigned*)((char*)d_ws + 2 * IMG_BYTES);

  const bool use_bits = (ws_size >= 2 * IMG_BYTES + BITS_BYTES);
  const int  grid = PREP_BLKS + (use_bits ? MASK_BLKS : 0);

  prep_kernel<<<grid, 256, 0, stream>>>(k, v, mask, kimg, vimg, bits);
  if (use_bits) {
    attn_kernel<true><<<BH_ * 32, 256, 0, stream>>>(q, bits, mask, kimg, vimg,
                                                    (float*)d_out);
  } else {
    attn_kernel<false><<<BH_ * 32, 256, 0, stream>>>(q, bits, mask, kimg, vimg,
                                                     (float*)d_out);
  }
}